// Round 1
// 295.644 us; speedup vs baseline: 1.2087x; 1.2087x over previous
//
#include <hip/hip_runtime.h>

#define NA 4096
#define NB 4096
#define DIM 256
#define DK 64
#define PSTR 72            // pbuf row stride (bf16 elements)
#define WSTR 68            // wm LDS row stride (f32 elements)
#define NSPLIT 4           // b-range splits (grid.y)
#define BIT (NB / NSPLIT / 64)   // 16 K-iterations per block

typedef __attribute__((ext_vector_type(8))) short bf16x8;
typedef __attribute__((ext_vector_type(4))) float f32x4;
typedef __attribute__((ext_vector_type(4))) unsigned short us4;
typedef __attribute__((ext_vector_type(4))) int i32x4;

static __device__ __forceinline__ float bf2f(unsigned short u) {
    union { unsigned int u; float f; } x;
    x.u = ((unsigned int)u) << 16;
    return x.f;
}
static __device__ __forceinline__ unsigned short f2bf(float f) {
    union { float f; unsigned int u; } x;
    x.f = f;
    unsigned int r = x.u + 0x7fffu + ((x.u >> 16) & 1u);
    return (unsigned short)(r >> 16);
}

// ---------------------------------------------------------------------------
// prep: elementwise fp32 -> (bf16 hi, bf16 lo) split of a_z, bv_z, Wq/Wk/Wv.
// Hoists the split VALU out of the GEMM (it was ~2900 VALU ops/lane there,
// recomputed 4x per wave). Pure streaming: ~17 MB -> ~3 us.
// ---------------------------------------------------------------------------
__global__ __launch_bounds__(256) void prep_kernel(
    const float* __restrict__ a_z, const float* __restrict__ bv,
    const float* __restrict__ Wq, const float* __restrict__ Wk,
    const float* __restrict__ Wv,
    unsigned short* __restrict__ ah, unsigned short* __restrict__ al,
    unsigned short* __restrict__ bh, unsigned short* __restrict__ bl,
    unsigned short* __restrict__ wh, unsigned short* __restrict__ wl)
{
    const int e = (blockIdx.x * 256 + threadIdx.x) * 4;
    const int which = blockIdx.y;
    const float* __restrict__ src;
    unsigned short* __restrict__ dh;
    unsigned short* __restrict__ dl;
    int off = e;
    if (which == 0)      { src = a_z; dh = ah; dl = al; }
    else if (which == 1) { src = bv;  dh = bh; dl = bl; }
    else {
        if (e >= 3 * DIM * DIM) return;
        src = (e < DIM * DIM) ? Wq : ((e < 2 * DIM * DIM) ? Wk : Wv);
        off = e & (DIM * DIM - 1);
        dh = wh; dl = wl;
    }
    f32x4 v = *(const f32x4*)(src + off);
    us4 h4, l4;
    #pragma unroll
    for (int r = 0; r < 4; ++r) {
        unsigned short h = f2bf(v[r]);
        h4[r] = h;
        l4[r] = f2bf(v[r] - bf2f(h));
    }
    *(us4*)(dh + e) = h4;
    *(us4*)(dl + e) = l4;
}

// ---------------------------------------------------------------------------
// proj: pure bf16 MFMA GEMM on pre-split operands.
//   X*W^T ~= xh*wh + xl*wh + xh*wl   (same term order as v1 -> bit-identical)
// mat 0: q -> qhi+qlo ; mat 1: k -> khi ; mat 2: v -> vt (transposed)
// ---------------------------------------------------------------------------
__global__ __launch_bounds__(256) void proj_kernel(
    const unsigned short* __restrict__ ah, const unsigned short* __restrict__ al,
    const unsigned short* __restrict__ bh, const unsigned short* __restrict__ bl,
    const unsigned short* __restrict__ whc, const unsigned short* __restrict__ wlc,
    unsigned short* __restrict__ qhi, unsigned short* __restrict__ qlo,
    unsigned short* __restrict__ khi, unsigned short* __restrict__ vtout)
{
    const int mat = blockIdx.z;
    const unsigned short* __restrict__ Xh = (mat == 0) ? ah : bh;
    const unsigned short* __restrict__ Xl = (mat == 0) ? al : bl;
    const unsigned short* __restrict__ Wh = whc + mat * DIM * DIM;
    const unsigned short* __restrict__ Wl = wlc + mat * DIM * DIM;

    const int tid  = threadIdx.x;
    const int wv   = tid >> 6;
    const int lane = tid & 63;
    const int c    = lane & 15;
    const int quad = lane >> 4;
    const int n0 = blockIdx.x * 64;
    const int j0 = blockIdx.y * 64 + wv * 16;

    f32x4 acc[4];
    #pragma unroll
    for (int nt = 0; nt < 4; ++nt) acc[nt] = (f32x4){0.f, 0.f, 0.f, 0.f};

    for (int ki = 0; ki < 8; ++ki) {
        const int i0 = ki * 32 + quad * 8;
        bf16x8 wfh = *(const bf16x8*)(Wh + (j0 + c) * DIM + i0);
        bf16x8 wfl = *(const bf16x8*)(Wl + (j0 + c) * DIM + i0);
        #pragma unroll
        for (int nt = 0; nt < 4; ++nt) {
            bf16x8 xh = *(const bf16x8*)(Xh + (n0 + nt * 16 + c) * DIM + i0);
            bf16x8 xl = *(const bf16x8*)(Xl + (n0 + nt * 16 + c) * DIM + i0);
            acc[nt] = __builtin_amdgcn_mfma_f32_16x16x32_bf16(xh, wfh, acc[nt], 0, 0, 0);
            acc[nt] = __builtin_amdgcn_mfma_f32_16x16x32_bf16(xl, wfh, acc[nt], 0, 0, 0);
            acc[nt] = __builtin_amdgcn_mfma_f32_16x16x32_bf16(xh, wfl, acc[nt], 0, 0, 0);
        }
    }

    // C/D layout: col = lane&15 (j), row = quad*4 + r (n)
    if (mat == 0) {
        #pragma unroll
        for (int nt = 0; nt < 4; ++nt)
            #pragma unroll
            for (int r = 0; r < 4; ++r) {
                const int idx = (n0 + nt * 16 + quad * 4 + r) * DIM + j0 + c;
                unsigned short h = f2bf(acc[nt][r]);
                qhi[idx] = h;
                qlo[idx] = f2bf(acc[nt][r] - bf2f(h));
            }
    } else if (mat == 1) {
        #pragma unroll
        for (int nt = 0; nt < 4; ++nt)
            #pragma unroll
            for (int r = 0; r < 4; ++r)
                khi[(n0 + nt * 16 + quad * 4 + r) * DIM + j0 + c] = f2bf(acc[nt][r]);
    } else {
        #pragma unroll
        for (int nt = 0; nt < 4; ++nt) {
            us4 p;
            #pragma unroll
            for (int r = 0; r < 4; ++r) p[r] = f2bf(acc[nt][r]);
            *(us4*)(vtout + (j0 + c) * NB + n0 + nt * 16 + quad * 4) = p;
        }
    }
}

// ---------------------------------------------------------------------------
// Fused attention, restructured for occupancy + MLP + traffic:
//  grid (256 a-tiles, NSPLIT b-splits) = 1024 blocks; 256 thr = 4 waves = 4 heads
//  -> 4 blocks/CU, 16 waves/CU (was 1 block/CU, 8 waves).
//  w+mask folded into ONE LDS tile (wm = m ? w : -1e9; clip -> -10 exactly),
//  staged once per block and shared by all 4 head-waves (4x less w/m traffic,
//  mask loads deleted from the hot loop). Double-buffered, one barrier/iter,
//  next-tile loads issued at top of body. Partial num/den -> workspace.
// ---------------------------------------------------------------------------
__global__ __launch_bounds__(256, 4) void attn_kernel(
    const unsigned short* __restrict__ qhg,
    const unsigned short* __restrict__ qlg,
    const unsigned short* __restrict__ kg,
    const unsigned short* __restrict__ vtg,
    const float* __restrict__ wg,
    const int* __restrict__ mg,
    float* __restrict__ pnum,
    float* __restrict__ pden)
{
    __shared__ float wmbuf[2][16 * WSTR];
    __shared__ unsigned short pbuf[4][16 * PSTR];

    const int tid  = threadIdx.x;
    const int wv   = tid >> 6;      // head
    const int lane = tid & 63;
    const int c    = lane & 15;
    const int quad = lane >> 4;

    // bijective XCD swizzle: each XCD gets one b-split x 128 contiguous a-tiles
    // -> its K/V quarter (1 MB) stays L2-resident. 1024 % 8 == 0.
    const int flat = blockIdx.y * 256 + blockIdx.x;
    const int swz  = (flat & 7) * 128 + (flat >> 3);
    const int a0   = (swz & 255) * 16;
    const int bs   = swz >> 8;
    const int bbase = bs * (NB / NSPLIT);

    // staging mapping: thread t handles (row sa, cols sb..sb+3) of 16x64 tile
    const int sa = tid >> 4;
    const int sb = (tid & 15) * 4;

    bf16x8 qh[2], ql[2];
    #pragma unroll
    for (int ks = 0; ks < 2; ++ks) {
        qh[ks] = *(const bf16x8*)(qhg + (a0 + c) * DIM + wv * DK + ks * 32 + quad * 8);
        ql[ks] = *(const bf16x8*)(qlg + (a0 + c) * DIM + wv * DK + ks * 32 + quad * 8);
    }

    f32x4 num[4];
    #pragma unroll
    for (int nt = 0; nt < 4; ++nt) num[nt] = (f32x4){0.f, 0.f, 0.f, 0.f};
    float den = 0.0f;

    // prologue: stage tile 0
    {
        const size_t off = (size_t)(a0 + sa) * NB + bbase + sb;
        f32x4 w = *(const f32x4*)(wg + off);
        i32x4 m = *(const i32x4*)(mg + off);
        f32x4 wm;
        #pragma unroll
        for (int r = 0; r < 4; ++r) wm[r] = m[r] ? w[r] : -1.0e9f;
        *(f32x4*)(&wmbuf[0][sa * WSTR + sb]) = wm;
    }

    for (int it = 0; it < BIT; ++it) {
        __syncthreads();   // wmbuf[cur] ready; wmbuf[cur^1] free to overwrite
        const int b0 = bbase + it * 64;
        const int cur = it & 1;
        const bool more = (it + 1 < BIT);

        // issue next-tile w/m loads early; consumed (ds_write) after PV
        f32x4 wnxt; i32x4 mnxt;
        if (more) {
            const size_t off = (size_t)(a0 + sa) * NB + b0 + 64 + sb;
            wnxt = *(const f32x4*)(wg + off);
            mnxt = *(const i32x4*)(mg + off);
        }

        bf16x8 kf[4][2];
        #pragma unroll
        for (int bt = 0; bt < 4; ++bt)
            #pragma unroll
            for (int ks = 0; ks < 2; ++ks)
                kf[bt][ks] = *(const bf16x8*)(kg + (b0 + bt * 16 + c) * DIM + wv * DK + ks * 32 + quad * 8);

        f32x4 wf[4];
        #pragma unroll
        for (int bt = 0; bt < 4; ++bt)
            wf[bt] = *(const f32x4*)(&wmbuf[cur][c * WSTR + bt * 16 + quad * 4]);

        // S^T[b][a]: A = K rows (m=b), B = Q rows (n=a); 2-term q split
        f32x4 S[4];
        __builtin_amdgcn_s_setprio(1);
        #pragma unroll
        for (int bt = 0; bt < 4; ++bt) {
            f32x4 s = (f32x4){0.f, 0.f, 0.f, 0.f};
            s = __builtin_amdgcn_mfma_f32_16x16x32_bf16(kf[bt][0], qh[0], s, 0, 0, 0);
            s = __builtin_amdgcn_mfma_f32_16x16x32_bf16(kf[bt][1], qh[1], s, 0, 0, 0);
            s = __builtin_amdgcn_mfma_f32_16x16x32_bf16(kf[bt][0], ql[0], s, 0, 0, 0);
            s = __builtin_amdgcn_mfma_f32_16x16x32_bf16(kf[bt][1], ql[1], s, 0, 0, 0);
            S[bt] = s;
        }
        __builtin_amdgcn_s_setprio(0);

        bf16x8 vf[4][2];
        #pragma unroll
        for (int nt = 0; nt < 4; ++nt)
            #pragma unroll
            for (int ks2 = 0; ks2 < 2; ++ks2)
                vf[nt][ks2] = *(const bf16x8*)(vtg + (wv * DK + nt * 16 + c) * NB + b0 + ks2 * 32 + quad * 8);

        // elementwise: lane holds (a = c, b = bt*16 + quad*4 + r)
        // wm already carries mask: masked -> -1e9 -> med3 -> exactly -10
        #pragma unroll
        for (int bt = 0; bt < 4; ++bt) {
            us4 p;
            #pragma unroll
            for (int r = 0; r < 4; ++r) {
                float t = fmaf(S[bt][r], 0.125f, wf[bt][r]);
                t = __builtin_amdgcn_fmed3f(t, -10.0f, 10.0f);
                float e = exp2f(t * 1.4426950408889634f);
                p[r] = f2bf(e);
                den += bf2f(p[r]);   // den consistent with bf16-rounded P
            }
            *(us4*)(&pbuf[wv][c * PSTR + bt * 16 + quad * 4]) = p;
        }

        // PV: A-frags from wave-private P (no barrier), B-frags from vt
        bf16x8 pf[2];
        #pragma unroll
        for (int ks2 = 0; ks2 < 2; ++ks2)
            pf[ks2] = *(const bf16x8*)(&pbuf[wv][c * PSTR + ks2 * 32 + quad * 8]);
        __builtin_amdgcn_s_setprio(1);
        #pragma unroll
        for (int nt = 0; nt < 4; ++nt) {
            num[nt] = __builtin_amdgcn_mfma_f32_16x16x32_bf16(pf[0], vf[nt][0], num[nt], 0, 0, 0);
            num[nt] = __builtin_amdgcn_mfma_f32_16x16x32_bf16(pf[1], vf[nt][1], num[nt], 0, 0, 0);
        }
        __builtin_amdgcn_s_setprio(0);

        // write next-tile staging (safe: all waves passed top-of-loop barrier)
        if (more) {
            f32x4 wm;
            #pragma unroll
            for (int r = 0; r < 4; ++r) wm[r] = mnxt[r] ? wnxt[r] : -1.0e9f;
            *(f32x4*)(&wmbuf[cur ^ 1][sa * WSTR + sb]) = wm;
        }
    }

    // den: sum across quads (lanes with same a = lane&15)
    den += __shfl_xor(den, 16, 64);
    den += __shfl_xor(den, 32, 64);
    const int hb = (bs * 4 + wv) * NA + a0;
    if (lane < 16) pden[hb + lane] = den;

    // num C-layout: col = lane&15 = dk-sub, row = quad*4+r = a
    #pragma unroll
    for (int nt = 0; nt < 4; ++nt)
        #pragma unroll
        for (int r = 0; r < 4; ++r)
            pnum[(size_t)(hb + quad * 4 + r) * DK + nt * 16 + c] = num[nt][r];
}

// ---------------------------------------------------------------------------
// reduce: combine b-split partials, divide, average heads; influence = 1.0
// ---------------------------------------------------------------------------
__global__ __launch_bounds__(256) void reduce_kernel(
    const float* __restrict__ pnum, const float* __restrict__ pden,
    float* __restrict__ outp)
{
    const int idx = blockIdx.x * 256 + threadIdx.x;   // over NA*DK
    const int a = idx >> 6, dd = idx & 63;
    float s = 0.0f;
    #pragma unroll
    for (int h = 0; h < 4; ++h) {
        float n = 0.0f, d = 0.0f;
        #pragma unroll
        for (int b = 0; b < NSPLIT; ++b) {
            n += pnum[(size_t)((b * 4 + h) * NA + a) * DK + dd];
            d += pden[(b * 4 + h) * NA + a];
        }
        s += n / d;
    }
    outp[idx] = 0.25f * s;
    if (dd == 0) outp[NA * DK + a] = 1.0f;   // softmax rows sum to 1
}

extern "C" void kernel_launch(void* const* d_in, const int* in_sizes, int n_in,
                              void* d_out, int out_size, void* d_ws, size_t ws_size,
                              hipStream_t stream) {
    const float* a_z = (const float*)d_in[0];
    const float* bv  = (const float*)d_in[1];
    const int* mask  = (const int*)d_in[2];
    const float* wgt = (const float*)d_in[3];
    const float* Wq  = (const float*)d_in[4];
    const float* Wk  = (const float*)d_in[5];
    const float* Wv  = (const float*)d_in[6];
    float* out = (float*)d_out;

    unsigned short* qhi = (unsigned short*)d_ws;       // [4096][256]
    unsigned short* qlo = qhi + NA * DIM;              // [4096][256]
    unsigned short* khi = qlo + NA * DIM;              // [4096][256]
    unsigned short* vt  = khi + NB * DIM;              // [256][4096]
    unsigned short* ah  = vt  + DIM * NB;              // [4096][256]
    unsigned short* al  = ah  + NA * DIM;
    unsigned short* bh  = al  + NA * DIM;
    unsigned short* bl  = bh  + NB * DIM;
    unsigned short* whc = bl  + NB * DIM;              // [3][256][256]
    unsigned short* wlc = whc + 3 * DIM * DIM;
    float* pnum = (float*)(wlc + 3 * DIM * DIM);       // [NSPLIT][4][NA][DK]
    float* pden = pnum + (size_t)NSPLIT * 4 * NA * DK; // [NSPLIT][4][NA]

    prep_kernel<<<dim3(1024, 3), 256, 0, stream>>>(a_z, bv, Wq, Wk, Wv,
                                                   ah, al, bh, bl, whc, wlc);
    proj_kernel<<<dim3(64, 4, 3), 256, 0, stream>>>(ah, al, bh, bl, whc, wlc,
                                                    qhi, qlo, khi, vt);
    attn_kernel<<<dim3(256, NSPLIT), 256, 0, stream>>>(qhi, qlo, khi, vt,
                                                       wgt, mask, pnum, pden);
    reduce_kernel<<<dim3(NA * DK / 256), 256, 0, stream>>>(pnum, pden, out);
}

// Round 2
// 293.775 us; speedup vs baseline: 1.2164x; 1.0064x over previous
//
#include <hip/hip_runtime.h>

#define NA 4096
#define NB 4096
#define DIM 256
#define DK 64
#define PSTR 72            // pbuf row stride (bf16 elements)
#define WSTR 68            // wm LDS row stride (f32 elements)
#define NSPLIT 4           // b-range splits (grid.y)
#define BIT (NB / NSPLIT / 64)   // 16 K-iterations per block

typedef __attribute__((ext_vector_type(8))) short bf16x8;
typedef __attribute__((ext_vector_type(4))) float f32x4;
typedef __attribute__((ext_vector_type(4))) unsigned short us4;
typedef __attribute__((ext_vector_type(4))) int i32x4;

static __device__ __forceinline__ float bf2f(unsigned short u) {
    union { unsigned int u; float f; } x;
    x.u = ((unsigned int)u) << 16;
    return x.f;
}
static __device__ __forceinline__ unsigned short f2bf(float f) {
    union { float f; unsigned int u; } x;
    x.f = f;
    unsigned int r = x.u + 0x7fffu + ((x.u >> 16) & 1u);
    return (unsigned short)(r >> 16);
}

// ---------------------------------------------------------------------------
// prep: elementwise fp32 -> (bf16 hi, bf16 lo) split of a_z, bv_z, Wq/Wk/Wv.
// ---------------------------------------------------------------------------
__global__ __launch_bounds__(256) void prep_kernel(
    const float* __restrict__ a_z, const float* __restrict__ bv,
    const float* __restrict__ Wq, const float* __restrict__ Wk,
    const float* __restrict__ Wv,
    unsigned short* __restrict__ ah, unsigned short* __restrict__ al,
    unsigned short* __restrict__ bh, unsigned short* __restrict__ bl,
    unsigned short* __restrict__ wh, unsigned short* __restrict__ wl)
{
    const int e = (blockIdx.x * 256 + threadIdx.x) * 4;
    const int which = blockIdx.y;
    const float* __restrict__ src;
    unsigned short* __restrict__ dh;
    unsigned short* __restrict__ dl;
    int off = e;
    if (which == 0)      { src = a_z; dh = ah; dl = al; }
    else if (which == 1) { src = bv;  dh = bh; dl = bl; }
    else {
        if (e >= 3 * DIM * DIM) return;
        src = (e < DIM * DIM) ? Wq : ((e < 2 * DIM * DIM) ? Wk : Wv);
        off = e & (DIM * DIM - 1);
        dh = wh; dl = wl;
    }
    f32x4 v = *(const f32x4*)(src + off);
    us4 h4, l4;
    #pragma unroll
    for (int r = 0; r < 4; ++r) {
        unsigned short h = f2bf(v[r]);
        h4[r] = h;
        l4[r] = f2bf(v[r] - bf2f(h));
    }
    *(us4*)(dh + e) = h4;
    *(us4*)(dl + e) = l4;
}

// ---------------------------------------------------------------------------
// proj: pure bf16 MFMA GEMM on pre-split operands.
//   X*W^T ~= xh*wh + xl*wh + xh*wl   (same term order as v1 -> bit-identical)
// ki loop fully unrolled + (256,2) bounds so loads can stay in flight.
// ---------------------------------------------------------------------------
__global__ __launch_bounds__(256, 2) void proj_kernel(
    const unsigned short* __restrict__ ah, const unsigned short* __restrict__ al,
    const unsigned short* __restrict__ bh, const unsigned short* __restrict__ bl,
    const unsigned short* __restrict__ whc, const unsigned short* __restrict__ wlc,
    unsigned short* __restrict__ qhi, unsigned short* __restrict__ qlo,
    unsigned short* __restrict__ khi, unsigned short* __restrict__ vtout)
{
    const int mat = blockIdx.z;
    const unsigned short* __restrict__ Xh = (mat == 0) ? ah : bh;
    const unsigned short* __restrict__ Xl = (mat == 0) ? al : bl;
    const unsigned short* __restrict__ Wh = whc + mat * DIM * DIM;
    const unsigned short* __restrict__ Wl = wlc + mat * DIM * DIM;

    const int tid  = threadIdx.x;
    const int wv   = tid >> 6;
    const int lane = tid & 63;
    const int c    = lane & 15;
    const int quad = lane >> 4;
    const int n0 = blockIdx.x * 64;
    const int j0 = blockIdx.y * 64 + wv * 16;

    f32x4 acc[4];
    #pragma unroll
    for (int nt = 0; nt < 4; ++nt) acc[nt] = (f32x4){0.f, 0.f, 0.f, 0.f};

    #pragma unroll
    for (int ki = 0; ki < 8; ++ki) {
        const int i0 = ki * 32 + quad * 8;
        bf16x8 wfh = *(const bf16x8*)(Wh + (j0 + c) * DIM + i0);
        bf16x8 wfl = *(const bf16x8*)(Wl + (j0 + c) * DIM + i0);
        #pragma unroll
        for (int nt = 0; nt < 4; ++nt) {
            bf16x8 xh = *(const bf16x8*)(Xh + (n0 + nt * 16 + c) * DIM + i0);
            bf16x8 xl = *(const bf16x8*)(Xl + (n0 + nt * 16 + c) * DIM + i0);
            acc[nt] = __builtin_amdgcn_mfma_f32_16x16x32_bf16(xh, wfh, acc[nt], 0, 0, 0);
            acc[nt] = __builtin_amdgcn_mfma_f32_16x16x32_bf16(xl, wfh, acc[nt], 0, 0, 0);
            acc[nt] = __builtin_amdgcn_mfma_f32_16x16x32_bf16(xh, wfl, acc[nt], 0, 0, 0);
        }
    }

    // C/D layout: col = lane&15 (j), row = quad*4 + r (n)
    if (mat == 0) {
        #pragma unroll
        for (int nt = 0; nt < 4; ++nt)
            #pragma unroll
            for (int r = 0; r < 4; ++r) {
                const int idx = (n0 + nt * 16 + quad * 4 + r) * DIM + j0 + c;
                unsigned short h = f2bf(acc[nt][r]);
                qhi[idx] = h;
                qlo[idx] = f2bf(acc[nt][r] - bf2f(h));
            }
    } else if (mat == 1) {
        #pragma unroll
        for (int nt = 0; nt < 4; ++nt)
            #pragma unroll
            for (int r = 0; r < 4; ++r)
                khi[(n0 + nt * 16 + quad * 4 + r) * DIM + j0 + c] = f2bf(acc[nt][r]);
    } else {
        #pragma unroll
        for (int nt = 0; nt < 4; ++nt) {
            us4 p;
            #pragma unroll
            for (int r = 0; r < 4; ++r) p[r] = f2bf(acc[nt][r]);
            *(us4*)(vtout + (j0 + c) * NB + n0 + nt * 16 + quad * 4) = p;
        }
    }
}

// ---------------------------------------------------------------------------
// Fused attention, v2: explicit register software pipeline.
//  - K tile double-buffered in registers (kA/kB, manual 2x unroll, all
//    compile-time indices) -> next tile's loads in flight across the barrier.
//  - V tile issued at top of body, consumed ~600cy later at PV.
//  - w/m next tile issued at top, LDS-written after PV (T14).
//  - sched_barrier(0) pins the issue block against compiler sinking.
//  - (256,2): cap 256 VGPR so the in-flight values can actually stay live
//    (round-1's (256,4) forced VGPR=64 -> serialized loads -> 95% stall).
// ---------------------------------------------------------------------------
__global__ __launch_bounds__(256, 2) void attn_kernel(
    const unsigned short* __restrict__ qhg,
    const unsigned short* __restrict__ qlg,
    const unsigned short* __restrict__ kg,
    const unsigned short* __restrict__ vtg,
    const float* __restrict__ wg,
    const int* __restrict__ mg,
    float* __restrict__ pnum,
    float* __restrict__ pden)
{
    __shared__ float wmbuf[2][16 * WSTR];
    __shared__ unsigned short pbuf[4][16 * PSTR];

    const int tid  = threadIdx.x;
    const int wv   = tid >> 6;      // head
    const int lane = tid & 63;
    const int c    = lane & 15;
    const int quad = lane >> 4;

    // bijective XCD swizzle: each XCD gets one b-split x 128 contiguous a-tiles
    const int flat = blockIdx.y * 256 + blockIdx.x;
    const int swz  = (flat & 7) * 128 + (flat >> 3);
    const int a0   = (swz & 255) * 16;
    const int bs   = swz >> 8;
    const int bbase = bs * (NB / NSPLIT);

    // staging mapping: thread t handles (row sa, cols sb..sb+3) of 16x64 tile
    const int sa = tid >> 4;
    const int sb = (tid & 15) * 4;

    bf16x8 qh[2], ql[2];
    #pragma unroll
    for (int ks = 0; ks < 2; ++ks) {
        qh[ks] = *(const bf16x8*)(qhg + (a0 + c) * DIM + wv * DK + ks * 32 + quad * 8);
        ql[ks] = *(const bf16x8*)(qlg + (a0 + c) * DIM + wv * DK + ks * 32 + quad * 8);
    }

    f32x4 num[4];
    #pragma unroll
    for (int nt = 0; nt < 4; ++nt) num[nt] = (f32x4){0.f, 0.f, 0.f, 0.f};
    float den = 0.0f;

    // prologue: stage wm tile 0 and K tile 0
    {
        const size_t off = (size_t)(a0 + sa) * NB + bbase + sb;
        f32x4 w = *(const f32x4*)(wg + off);
        i32x4 m = *(const i32x4*)(mg + off);
        f32x4 wm;
        #pragma unroll
        for (int r = 0; r < 4; ++r) wm[r] = m[r] ? w[r] : -1.0e9f;
        *(f32x4*)(&wmbuf[0][sa * WSTR + sb]) = wm;
    }
    bf16x8 kA[4][2], kB[4][2];
    #pragma unroll
    for (int bt = 0; bt < 4; ++bt)
        #pragma unroll
        for (int ks = 0; ks < 2; ++ks)
            kA[bt][ks] = *(const bf16x8*)(kg + (bbase + bt * 16 + c) * DIM + wv * DK + ks * 32 + quad * 8);

#define ITER(IT, KCUR, KNXT, CUR)                                              \
    {                                                                          \
        const int b0 = bbase + (IT) * 64;                                      \
        const bool more = ((IT) + 1 < BIT);                                    \
        __syncthreads();  /* wmbuf[CUR] ready; wmbuf[CUR^1] free */            \
        /* --- issue block: next w/m, next K, current V --- */                 \
        f32x4 wnxt; i32x4 mnxt;                                                \
        if (more) {                                                            \
            const size_t off = (size_t)(a0 + sa) * NB + b0 + 64 + sb;          \
            wnxt = *(const f32x4*)(wg + off);                                  \
            mnxt = *(const i32x4*)(mg + off);                                  \
            _Pragma("unroll")                                                  \
            for (int bt = 0; bt < 4; ++bt)                                     \
                _Pragma("unroll")                                              \
                for (int ks = 0; ks < 2; ++ks)                                 \
                    KNXT[bt][ks] = *(const bf16x8*)(kg + (b0 + 64 + bt * 16 + c) * DIM + wv * DK + ks * 32 + quad * 8); \
        }                                                                      \
        bf16x8 vf[4][2];                                                       \
        _Pragma("unroll")                                                      \
        for (int nt = 0; nt < 4; ++nt)                                         \
            _Pragma("unroll")                                                  \
            for (int ks2 = 0; ks2 < 2; ++ks2)                                  \
                vf[nt][ks2] = *(const bf16x8*)(vtg + (wv * DK + nt * 16 + c) * NB + b0 + ks2 * 32 + quad * 8); \
        __builtin_amdgcn_sched_barrier(0);  /* pin issue order */              \
        /* --- wm fragments from LDS --- */                                    \
        f32x4 wf[4];                                                           \
        _Pragma("unroll")                                                      \
        for (int bt = 0; bt < 4; ++bt)                                         \
            wf[bt] = *(const f32x4*)(&wmbuf[CUR][c * WSTR + bt * 16 + quad * 4]); \
        /* --- S^T = K*(Qhi)^T + K*(Qlo)^T --- */                              \
        f32x4 S[4];                                                            \
        __builtin_amdgcn_s_setprio(1);                                         \
        _Pragma("unroll")                                                      \
        for (int bt = 0; bt < 4; ++bt) {                                       \
            f32x4 s = (f32x4){0.f, 0.f, 0.f, 0.f};                             \
            s = __builtin_amdgcn_mfma_f32_16x16x32_bf16(KCUR[bt][0], qh[0], s, 0, 0, 0); \
            s = __builtin_amdgcn_mfma_f32_16x16x32_bf16(KCUR[bt][1], qh[1], s, 0, 0, 0); \
            s = __builtin_amdgcn_mfma_f32_16x16x32_bf16(KCUR[bt][0], ql[0], s, 0, 0, 0); \
            s = __builtin_amdgcn_mfma_f32_16x16x32_bf16(KCUR[bt][1], ql[1], s, 0, 0, 0); \
            S[bt] = s;                                                         \
        }                                                                      \
        __builtin_amdgcn_s_setprio(0);                                         \
        /* --- elementwise: lane holds (a = c, b = bt*16 + quad*4 + r) --- */  \
        _Pragma("unroll")                                                      \
        for (int bt = 0; bt < 4; ++bt) {                                       \
            us4 p;                                                             \
            _Pragma("unroll")                                                  \
            for (int r = 0; r < 4; ++r) {                                      \
                float t = fmaf(S[bt][r], 0.125f, wf[bt][r]);                   \
                t = __builtin_amdgcn_fmed3f(t, -10.0f, 10.0f);                 \
                float e = exp2f(t * 1.4426950408889634f);                      \
                p[r] = f2bf(e);                                                \
                den += bf2f(p[r]);                                             \
            }                                                                  \
            *(us4*)(&pbuf[wv][c * PSTR + bt * 16 + quad * 4]) = p;             \
        }                                                                      \
        /* --- PV --- */                                                       \
        bf16x8 pf[2];                                                          \
        _Pragma("unroll")                                                      \
        for (int ks2 = 0; ks2 < 2; ++ks2)                                      \
            pf[ks2] = *(const bf16x8*)(&pbuf[wv][c * PSTR + ks2 * 32 + quad * 8]); \
        __builtin_amdgcn_s_setprio(1);                                         \
        _Pragma("unroll")                                                      \
        for (int nt = 0; nt < 4; ++nt) {                                       \
            num[nt] = __builtin_amdgcn_mfma_f32_16x16x32_bf16(pf[0], vf[nt][0], num[nt], 0, 0, 0); \
            num[nt] = __builtin_amdgcn_mfma_f32_16x16x32_bf16(pf[1], vf[nt][1], num[nt], 0, 0, 0); \
        }                                                                      \
        __builtin_amdgcn_s_setprio(0);                                         \
        /* --- write next wm tile (all waves passed top barrier) --- */        \
        if (more) {                                                            \
            f32x4 wm;                                                          \
            _Pragma("unroll")                                                  \
            for (int r = 0; r < 4; ++r) wm[r] = mnxt[r] ? wnxt[r] : -1.0e9f;   \
            *(f32x4*)(&wmbuf[(CUR) ^ 1][sa * WSTR + sb]) = wm;                 \
        }                                                                      \
    }

    for (int ito = 0; ito < BIT; ito += 2) {
        ITER(ito,     kA, kB, 0)
        ITER(ito + 1, kB, kA, 1)
    }
#undef ITER

    // den: sum across quads (lanes with same a = lane&15)
    den += __shfl_xor(den, 16, 64);
    den += __shfl_xor(den, 32, 64);
    const int hb = (bs * 4 + wv) * NA + a0;
    if (lane < 16) pden[hb + lane] = den;

    // num C-layout: col = lane&15 = dk-sub, row = quad*4+r = a
    #pragma unroll
    for (int nt = 0; nt < 4; ++nt)
        #pragma unroll
        for (int r = 0; r < 4; ++r)
            pnum[(size_t)(hb + quad * 4 + r) * DK + nt * 16 + c] = num[nt][r];
}

// ---------------------------------------------------------------------------
// reduce: combine b-split partials, divide, average heads; influence = 1.0
// ---------------------------------------------------------------------------
__global__ __launch_bounds__(256) void reduce_kernel(
    const float* __restrict__ pnum, const float* __restrict__ pden,
    float* __restrict__ outp)
{
    const int idx = blockIdx.x * 256 + threadIdx.x;   // over NA*DK
    const int a = idx >> 6, dd = idx & 63;
    float s = 0.0f;
    #pragma unroll
    for (int h = 0; h < 4; ++h) {
        float n = 0.0f, d = 0.0f;
        #pragma unroll
        for (int b = 0; b < NSPLIT; ++b) {
            n += pnum[(size_t)((b * 4 + h) * NA + a) * DK + dd];
            d += pden[(b * 4 + h) * NA + a];
        }
        s += n / d;
    }
    outp[idx] = 0.25f * s;
    if (dd == 0) outp[NA * DK + a] = 1.0f;   // softmax rows sum to 1
}

extern "C" void kernel_launch(void* const* d_in, const int* in_sizes, int n_in,
                              void* d_out, int out_size, void* d_ws, size_t ws_size,
                              hipStream_t stream) {
    const float* a_z = (const float*)d_in[0];
    const float* bv  = (const float*)d_in[1];
    const int* mask  = (const int*)d_in[2];
    const float* wgt = (const float*)d_in[3];
    const float* Wq  = (const float*)d_in[4];
    const float* Wk  = (const float*)d_in[5];
    const float* Wv  = (const float*)d_in[6];
    float* out = (float*)d_out;

    unsigned short* qhi = (unsigned short*)d_ws;       // [4096][256]
    unsigned short* qlo = qhi + NA * DIM;              // [4096][256]
    unsigned short* khi = qlo + NA * DIM;              // [4096][256]
    unsigned short* vt  = khi + NB * DIM;              // [256][4096]
    unsigned short* ah  = vt  + DIM * NB;              // [4096][256]
    unsigned short* al  = ah  + NA * DIM;
    unsigned short* bh  = al  + NA * DIM;
    unsigned short* bl  = bh  + NB * DIM;
    unsigned short* whc = bl  + NB * DIM;              // [3][256][256]
    unsigned short* wlc = whc + 3 * DIM * DIM;
    float* pnum = (float*)(wlc + 3 * DIM * DIM);       // [NSPLIT][4][NA][DK]
    float* pden = pnum + (size_t)NSPLIT * 4 * NA * DK; // [NSPLIT][4][NA]

    prep_kernel<<<dim3(1024, 3), 256, 0, stream>>>(a_z, bv, Wq, Wk, Wv,
                                                   ah, al, bh, bl, whc, wlc);
    proj_kernel<<<dim3(64, 4, 3), 256, 0, stream>>>(ah, al, bh, bl, whc, wlc,
                                                    qhi, qlo, khi, vt);
    attn_kernel<<<dim3(256, NSPLIT), 256, 0, stream>>>(qhi, qlo, khi, vt,
                                                       wgt, mask, pnum, pden);
    reduce_kernel<<<dim3(NA * DK / 256), 256, 0, stream>>>(pnum, pden, out);
}

// Round 4
// 285.223 us; speedup vs baseline: 1.2528x; 1.0300x over previous
//
#include <hip/hip_runtime.h>

#define NA 4096
#define NB 4096
#define DIM 256
#define DK 64
#define PSTR 72            // pbuf row stride (bf16 elements)
#define WSTR 68            // wm LDS row stride (f32 elements)
#define NSPLIT 4           // b-range splits (grid.y)
#define BIT (NB / NSPLIT / 64)   // 16 K-iterations per block

typedef __attribute__((ext_vector_type(8))) short bf16x8;
typedef __attribute__((ext_vector_type(4))) float f32x4;
typedef __attribute__((ext_vector_type(4))) unsigned short us4;
typedef __attribute__((ext_vector_type(4))) int i32x4;

static __device__ __forceinline__ float bf2f(unsigned short u) {
    union { unsigned int u; float f; } x;
    x.u = ((unsigned int)u) << 16;
    return x.f;
}
static __device__ __forceinline__ unsigned short f2bf(float f) {
    union { float f; unsigned int u; } x;
    x.f = f;
    unsigned int r = x.u + 0x7fffu + ((x.u >> 16) & 1u);
    return (unsigned short)(r >> 16);
}

// ---------------------------------------------------------------------------
// prep: elementwise fp32 -> (bf16 hi, bf16 lo) split of a_z, bv_z, Wq/Wk/Wv.
// ---------------------------------------------------------------------------
__global__ __launch_bounds__(256) void prep_kernel(
    const float* __restrict__ a_z, const float* __restrict__ bv,
    const float* __restrict__ Wq, const float* __restrict__ Wk,
    const float* __restrict__ Wv,
    unsigned short* __restrict__ ah, unsigned short* __restrict__ al,
    unsigned short* __restrict__ bh, unsigned short* __restrict__ bl,
    unsigned short* __restrict__ wh, unsigned short* __restrict__ wl)
{
    const int e = (blockIdx.x * 256 + threadIdx.x) * 4;
    const int which = blockIdx.y;
    const float* __restrict__ src;
    unsigned short* __restrict__ dh;
    unsigned short* __restrict__ dl;
    int off = e;
    if (which == 0)      { src = a_z; dh = ah; dl = al; }
    else if (which == 1) { src = bv;  dh = bh; dl = bl; }
    else {
        if (e >= 3 * DIM * DIM) return;
        src = (e < DIM * DIM) ? Wq : ((e < 2 * DIM * DIM) ? Wk : Wv);
        off = e & (DIM * DIM - 1);
        dh = wh; dl = wl;
    }
    f32x4 v = *(const f32x4*)(src + off);
    us4 h4, l4;
    #pragma unroll
    for (int r = 0; r < 4; ++r) {
        unsigned short h = f2bf(v[r]);
        h4[r] = h;
        l4[r] = f2bf(v[r] - bf2f(h));
    }
    *(us4*)(dh + e) = h4;
    *(us4*)(dl + e) = l4;
}

// ---------------------------------------------------------------------------
// proj v3: software-pipelined A/B register double-buffer over ki.
// Row-base pointers precomputed; ki offsets are compile-time immediates.
// Per stage: 10 loads + 12 MFMA; ~135 VGPR, no spill (was: 80 loads fully
// unrolled with everything live -> spill/serialize suspicion).
//   X*W^T ~= xh*wh + xl*wh + xh*wl   (term order identical to prior rounds)
// ---------------------------------------------------------------------------
__global__ __launch_bounds__(256, 2) void proj_kernel(
    const unsigned short* __restrict__ ah, const unsigned short* __restrict__ al,
    const unsigned short* __restrict__ bh, const unsigned short* __restrict__ bl,
    const unsigned short* __restrict__ whc, const unsigned short* __restrict__ wlc,
    unsigned short* __restrict__ qhi, unsigned short* __restrict__ qlo,
    unsigned short* __restrict__ khi, unsigned short* __restrict__ vtout)
{
    const int mat = blockIdx.z;
    const unsigned short* __restrict__ Xh = (mat == 0) ? ah : bh;
    const unsigned short* __restrict__ Xl = (mat == 0) ? al : bl;
    const unsigned short* __restrict__ Wh = whc + mat * DIM * DIM;
    const unsigned short* __restrict__ Wl = wlc + mat * DIM * DIM;

    const int tid  = threadIdx.x;
    const int wv   = tid >> 6;
    const int lane = tid & 63;
    const int c    = lane & 15;
    const int quad = lane >> 4;
    const int n0 = blockIdx.x * 64;
    const int j0 = blockIdx.y * 64 + wv * 16;

    const unsigned short* pwh = Wh + (j0 + c) * DIM + quad * 8;
    const unsigned short* pwl = Wl + (j0 + c) * DIM + quad * 8;
    const unsigned short* pxh[4];
    const unsigned short* pxl[4];
    #pragma unroll
    for (int nt = 0; nt < 4; ++nt) {
        pxh[nt] = Xh + (n0 + nt * 16 + c) * DIM + quad * 8;
        pxl[nt] = Xl + (n0 + nt * 16 + c) * DIM + quad * 8;
    }

    f32x4 acc[4];
    #pragma unroll
    for (int nt = 0; nt < 4; ++nt) acc[nt] = (f32x4){0.f, 0.f, 0.f, 0.f};

    bf16x8 wAh, wAl, xAh[4], xAl[4];
    bf16x8 wBh, wBl, xBh[4], xBl[4];

    // preload ki = 0
    wAh = *(const bf16x8*)(pwh);
    wAl = *(const bf16x8*)(pwl);
    #pragma unroll
    for (int nt = 0; nt < 4; ++nt) {
        xAh[nt] = *(const bf16x8*)(pxh[nt]);
        xAl[nt] = *(const bf16x8*)(pxl[nt]);
    }

    #pragma unroll
    for (int kk = 0; kk < 8; kk += 2) {
        // load B set (ki = kk+1) while computing on A
        wBh = *(const bf16x8*)(pwh + (kk + 1) * 32);
        wBl = *(const bf16x8*)(pwl + (kk + 1) * 32);
        #pragma unroll
        for (int nt = 0; nt < 4; ++nt) {
            xBh[nt] = *(const bf16x8*)(pxh[nt] + (kk + 1) * 32);
            xBl[nt] = *(const bf16x8*)(pxl[nt] + (kk + 1) * 32);
        }
        #pragma unroll
        for (int nt = 0; nt < 4; ++nt) {
            acc[nt] = __builtin_amdgcn_mfma_f32_16x16x32_bf16(xAh[nt], wAh, acc[nt], 0, 0, 0);
            acc[nt] = __builtin_amdgcn_mfma_f32_16x16x32_bf16(xAl[nt], wAh, acc[nt], 0, 0, 0);
            acc[nt] = __builtin_amdgcn_mfma_f32_16x16x32_bf16(xAh[nt], wAl, acc[nt], 0, 0, 0);
        }
        // load next A set (ki = kk+2) while computing on B
        if (kk + 2 < 8) {
            wAh = *(const bf16x8*)(pwh + (kk + 2) * 32);
            wAl = *(const bf16x8*)(pwl + (kk + 2) * 32);
            #pragma unroll
            for (int nt = 0; nt < 4; ++nt) {
                xAh[nt] = *(const bf16x8*)(pxh[nt] + (kk + 2) * 32);
                xAl[nt] = *(const bf16x8*)(pxl[nt] + (kk + 2) * 32);
            }
        }
        #pragma unroll
        for (int nt = 0; nt < 4; ++nt) {
            acc[nt] = __builtin_amdgcn_mfma_f32_16x16x32_bf16(xBh[nt], wBh, acc[nt], 0, 0, 0);
            acc[nt] = __builtin_amdgcn_mfma_f32_16x16x32_bf16(xBl[nt], wBh, acc[nt], 0, 0, 0);
            acc[nt] = __builtin_amdgcn_mfma_f32_16x16x32_bf16(xBh[nt], wBl, acc[nt], 0, 0, 0);
        }
    }

    // C/D layout: col = lane&15 (j), row = quad*4 + r (n)
    if (mat == 0) {
        #pragma unroll
        for (int nt = 0; nt < 4; ++nt)
            #pragma unroll
            for (int r = 0; r < 4; ++r) {
                const int idx = (n0 + nt * 16 + quad * 4 + r) * DIM + j0 + c;
                unsigned short h = f2bf(acc[nt][r]);
                qhi[idx] = h;
                qlo[idx] = f2bf(acc[nt][r] - bf2f(h));
            }
    } else if (mat == 1) {
        #pragma unroll
        for (int nt = 0; nt < 4; ++nt)
            #pragma unroll
            for (int r = 0; r < 4; ++r)
                khi[(n0 + nt * 16 + quad * 4 + r) * DIM + j0 + c] = f2bf(acc[nt][r]);
    } else {
        #pragma unroll
        for (int nt = 0; nt < 4; ++nt) {
            us4 p;
            #pragma unroll
            for (int r = 0; r < 4; ++r) p[r] = f2bf(acc[nt][r]);
            *(us4*)(vtout + (j0 + c) * NB + n0 + nt * 16 + quad * 4) = p;
        }
    }
}

// ---------------------------------------------------------------------------
// attn v3: vmcnt-ordered issue groups.
//  Issue order per iter: K (needed 1st) -> V (needed 2nd) -> next-w/m
//  (needed last), sched_barrier(0) fenced. QK's K-wait leaves V+wm in
//  flight; PV's V-wait leaves wm in flight; the wm ds_write drains only wm.
//  (Round-2 issued V last -> PV drained next-tile K + HBM-miss w/m every
//  iter = structural serialization.)
//  den via ones-column MFMA (removes 48 VALU + serial add chain per iter).
//  Strength-reduced u32 offsets kill per-iter 64-bit address VALU.
// ---------------------------------------------------------------------------
__global__ __launch_bounds__(256, 2) void attn_kernel(
    const unsigned short* __restrict__ qhg,
    const unsigned short* __restrict__ qlg,
    const unsigned short* __restrict__ kg,
    const unsigned short* __restrict__ vtg,
    const float* __restrict__ wg,
    const int* __restrict__ mg,
    float* __restrict__ pnum,
    float* __restrict__ pden)
{
    __shared__ float wmbuf[2][16 * WSTR];
    __shared__ unsigned short pbuf[4][16 * PSTR];

    const int tid  = threadIdx.x;
    const int wv   = tid >> 6;      // head
    const int lane = tid & 63;
    const int c    = lane & 15;
    const int quad = lane >> 4;

    // bijective XCD swizzle: each XCD gets one b-split x 128 contiguous a-tiles
    const int flat = blockIdx.y * 256 + blockIdx.x;
    const int swz  = (flat & 7) * 128 + (flat >> 3);
    const int a0   = (swz & 255) * 16;
    const int bs   = swz >> 8;
    const int bbase = bs * (NB / NSPLIT);

    // staging mapping: thread t handles (row sa, cols sb..sb+3) of 16x64 tile
    const int sa = tid >> 4;
    const int sb = (tid & 15) * 4;

    bf16x8 qh[2], ql[2];
    #pragma unroll
    for (int ks = 0; ks < 2; ++ks) {
        qh[ks] = *(const bf16x8*)(qhg + (a0 + c) * DIM + wv * DK + ks * 32 + quad * 8);
        ql[ks] = *(const bf16x8*)(qlg + (a0 + c) * DIM + wv * DK + ks * 32 + quad * 8);
    }

    // bf16 1.0 splat for the den (ones-column) MFMA
    bf16x8 ones;
    #pragma unroll
    for (int r = 0; r < 8; ++r) ones[r] = (short)0x3F80;

    f32x4 num[4];
    #pragma unroll
    for (int nt = 0; nt < 4; ++nt) num[nt] = (f32x4){0.f, 0.f, 0.f, 0.f};
    f32x4 dacc = (f32x4){0.f, 0.f, 0.f, 0.f};

    // strength-reduced offsets (u32 element indices)
    unsigned koff[4], voff[4];
    #pragma unroll
    for (int bt = 0; bt < 4; ++bt)
        koff[bt] = (unsigned)((bbase + bt * 16 + c) * DIM + wv * DK + quad * 8);
    #pragma unroll
    for (int nt = 0; nt < 4; ++nt)
        voff[nt] = (unsigned)((wv * DK + nt * 16 + c) * NB + bbase + quad * 8);
    unsigned woff = (unsigned)((a0 + sa) * NB + bbase + sb);

    // prologue: stage wm tile 0
    {
        f32x4 w = *(const f32x4*)(wg + woff);
        i32x4 m = *(const i32x4*)(mg + woff);
        f32x4 wm;
        #pragma unroll
        for (int r = 0; r < 4; ++r) wm[r] = m[r] ? w[r] : -1.0e9f;
        *(f32x4*)(&wmbuf[0][sa * WSTR + sb]) = wm;
    }
    woff += 64;

    for (int it = 0; it < BIT; ++it) {
        const int cur = it & 1;
        const bool more = (it + 1 < BIT);
        __syncthreads();   // wmbuf[cur] ready; wmbuf[cur^1] free

        // --- group 1: K loads (consumed first, at QK) ---
        bf16x8 kf[4][2];
        #pragma unroll
        for (int bt = 0; bt < 4; ++bt)
            #pragma unroll
            for (int ks = 0; ks < 2; ++ks)
                kf[bt][ks] = *(const bf16x8*)(kg + koff[bt] + ks * 32);
        __builtin_amdgcn_sched_barrier(0);

        // --- group 2: V loads (consumed at PV) ---
        bf16x8 vf[4][2];
        #pragma unroll
        for (int nt = 0; nt < 4; ++nt)
            #pragma unroll
            for (int ks2 = 0; ks2 < 2; ++ks2)
                vf[nt][ks2] = *(const bf16x8*)(vtg + voff[nt] + ks2 * 32);
        __builtin_amdgcn_sched_barrier(0);

        // --- group 3: next-tile w/m (consumed last, at the ds_write) ---
        f32x4 wnxt; i32x4 mnxt;
        if (more) {
            wnxt = *(const f32x4*)(wg + woff);
            mnxt = *(const i32x4*)(mg + woff);
        }
        __builtin_amdgcn_sched_barrier(0);

        // advance offsets (overlaps with waits)
        #pragma unroll
        for (int bt = 0; bt < 4; ++bt) koff[bt] += 64 * DIM;
        #pragma unroll
        for (int nt = 0; nt < 4; ++nt) voff[nt] += 64;
        woff += 64;

        // wm fragments from LDS
        f32x4 wf[4];
        #pragma unroll
        for (int bt = 0; bt < 4; ++bt)
            wf[bt] = *(const f32x4*)(&wmbuf[cur][c * WSTR + bt * 16 + quad * 4]);

        // S^T = K*(Qhi)^T + K*(Qlo)^T
        f32x4 S[4];
        __builtin_amdgcn_s_setprio(1);
        #pragma unroll
        for (int bt = 0; bt < 4; ++bt) {
            f32x4 s = (f32x4){0.f, 0.f, 0.f, 0.f};
            s = __builtin_amdgcn_mfma_f32_16x16x32_bf16(kf[bt][0], qh[0], s, 0, 0, 0);
            s = __builtin_amdgcn_mfma_f32_16x16x32_bf16(kf[bt][1], qh[1], s, 0, 0, 0);
            s = __builtin_amdgcn_mfma_f32_16x16x32_bf16(kf[bt][0], ql[0], s, 0, 0, 0);
            s = __builtin_amdgcn_mfma_f32_16x16x32_bf16(kf[bt][1], ql[1], s, 0, 0, 0);
            S[bt] = s;
        }
        __builtin_amdgcn_s_setprio(0);

        // elementwise: lane holds (a = c, b = bt*16 + quad*4 + r)
        #pragma unroll
        for (int bt = 0; bt < 4; ++bt) {
            us4 p;
            #pragma unroll
            for (int r = 0; r < 4; ++r) {
                float t = fmaf(S[bt][r], 0.125f, wf[bt][r]);
                t = __builtin_amdgcn_fmed3f(t, -10.0f, 10.0f);
                float e = exp2f(t * 1.4426950408889634f);
                p[r] = f2bf(e);
            }
            *(us4*)(&pbuf[wv][c * PSTR + bt * 16 + quad * 4]) = p;
        }

        // PV + den: A-frags from wave-private P (no barrier)
        bf16x8 pf[2];
        #pragma unroll
        for (int ks2 = 0; ks2 < 2; ++ks2)
            pf[ks2] = *(const bf16x8*)(&pbuf[wv][c * PSTR + ks2 * 32 + quad * 8]);
        __builtin_amdgcn_s_setprio(1);
        #pragma unroll
        for (int nt = 0; nt < 4; ++nt) {
            num[nt] = __builtin_amdgcn_mfma_f32_16x16x32_bf16(pf[0], vf[nt][0], num[nt], 0, 0, 0);
            num[nt] = __builtin_amdgcn_mfma_f32_16x16x32_bf16(pf[1], vf[nt][1], num[nt], 0, 0, 0);
        }
        dacc = __builtin_amdgcn_mfma_f32_16x16x32_bf16(pf[0], ones, dacc, 0, 0, 0);
        dacc = __builtin_amdgcn_mfma_f32_16x16x32_bf16(pf[1], ones, dacc, 0, 0, 0);
        __builtin_amdgcn_s_setprio(0);

        // write next wm tile (all waves passed top barrier; waits only on wm)
        if (more) {
            f32x4 wm;
            #pragma unroll
            for (int r = 0; r < 4; ++r) wm[r] = mnxt[r] ? wnxt[r] : -1.0e9f;
            *(f32x4*)(&wmbuf[cur ^ 1][sa * WSTR + sb]) = wm;
        }
    }

    // den: dacc C-layout row = quad*4+r = a, every col c holds a copy
    const int hb = (bs * 4 + wv) * NA + a0;
    if (c == 0) {
        #pragma unroll
        for (int r = 0; r < 4; ++r)
            pden[hb + quad * 4 + r] = dacc[r];
    }

    // num C-layout: col = lane&15 = dk-sub, row = quad*4+r = a
    #pragma unroll
    for (int nt = 0; nt < 4; ++nt)
        #pragma unroll
        for (int r = 0; r < 4; ++r)
            pnum[(size_t)(hb + quad * 4 + r) * DK + nt * 16 + c] = num[nt][r];
}

// ---------------------------------------------------------------------------
// reduce: combine b-split partials, divide, average heads; influence = 1.0
// ---------------------------------------------------------------------------
__global__ __launch_bounds__(256) void reduce_kernel(
    const float* __restrict__ pnum, const float* __restrict__ pden,
    float* __restrict__ outp)
{
    const int idx = blockIdx.x * 256 + threadIdx.x;   // over NA*DK
    const int a = idx >> 6, dd = idx & 63;
    float s = 0.0f;
    #pragma unroll
    for (int h = 0; h < 4; ++h) {
        float n = 0.0f, d = 0.0f;
        #pragma unroll
        for (int b = 0; b < NSPLIT; ++b) {
            n += pnum[(size_t)((b * 4 + h) * NA + a) * DK + dd];
            d += pden[(b * 4 + h) * NA + a];
        }
        s += n / d;
    }
    outp[idx] = 0.25f * s;
    if (dd == 0) outp[NA * DK + a] = 1.0f;   // softmax rows sum to 1
}

extern "C" void kernel_launch(void* const* d_in, const int* in_sizes, int n_in,
                              void* d_out, int out_size, void* d_ws, size_t ws_size,
                              hipStream_t stream) {
    const float* a_z = (const float*)d_in[0];
    const float* bv  = (const float*)d_in[1];
    const int* mask  = (const int*)d_in[2];
    const float* wgt = (const float*)d_in[3];
    const float* Wq  = (const float*)d_in[4];
    const float* Wk  = (const float*)d_in[5];
    const float* Wv  = (const float*)d_in[6];
    float* out = (float*)d_out;

    unsigned short* qhi = (unsigned short*)d_ws;       // [4096][256]
    unsigned short* qlo = qhi + NA * DIM;              // [4096][256]
    unsigned short* khi = qlo + NA * DIM;              // [4096][256]
    unsigned short* vt  = khi + NB * DIM;              // [256][4096]
    unsigned short* ah  = vt  + DIM * NB;              // [4096][256]
    unsigned short* al  = ah  + NA * DIM;
    unsigned short* bh  = al  + NA * DIM;
    unsigned short* bl  = bh  + NB * DIM;
    unsigned short* whc = bl  + NB * DIM;              // [3][256][256]
    unsigned short* wlc = whc + 3 * DIM * DIM;
    float* pnum = (float*)(wlc + 3 * DIM * DIM);       // [NSPLIT][4][NA][DK]
    float* pden = pnum + (size_t)NSPLIT * 4 * NA * DK; // [NSPLIT][4][NA]

    prep_kernel<<<dim3(1024, 3), 256, 0, stream>>>(a_z, bv, Wq, Wk, Wv,
                                                   ah, al, bh, bl, whc, wlc);
    proj_kernel<<<dim3(64, 4, 3), 256, 0, stream>>>(ah, al, bh, bl, whc, wlc,
                                                    qhi, qlo, khi, vt);
    attn_kernel<<<dim3(256, NSPLIT), 256, 0, stream>>>(qhi, qlo, khi, vt,
                                                       wgt, mask, pnum, pden);
    reduce_kernel<<<dim3(NA * DK / 256), 256, 0, stream>>>(pnum, pden, out);
}

// Round 5
// 215.796 us; speedup vs baseline: 1.6559x; 1.3217x over previous
//
#include <hip/hip_runtime.h>

#define NA 4096
#define NB 4096
#define DIM 256
#define DK 64
#define PSTR 72            // pbuf row stride (bf16 elements)
#define WSTR 68            // wm LDS row stride (f32 elements)
#define NSPLIT 8           // b-range splits (grid.y)
#define BIT (NB / NSPLIT / 64)   // 8 K-iterations per block

typedef __attribute__((ext_vector_type(8))) short bf16x8;
typedef __attribute__((ext_vector_type(4))) float f32x4;
typedef __attribute__((ext_vector_type(4))) unsigned short us4;
typedef __attribute__((ext_vector_type(4))) int i32x4;

static __device__ __forceinline__ float bf2f(unsigned short u) {
    union { unsigned int u; float f; } x;
    x.u = ((unsigned int)u) << 16;
    return x.f;
}
static __device__ __forceinline__ unsigned short f2bf(float f) {
    union { float f; unsigned int u; } x;
    x.f = f;
    unsigned int r = x.u + 0x7fffu + ((x.u >> 16) & 1u);
    return (unsigned short)(r >> 16);
}

// ---------------------------------------------------------------------------
// Fragment-major layouts (lane-contiguous: element for lane l at base+l*8):
//  XF/WF (proj inputs): flat = ((tile*8 + ki)*64 + l)*8 + e
//      holds  X[tile*16 + (l&15)][ki*32 + (l>>4)*8 + e]
//  QF/KF (attn QK):     flat = (((head*256 + t16)*2 + ks)*64 + l)*8 + e
//      holds  M[t16*16 + (l&15)][head*64 + ks*32 + (l>>4)*8 + e]
//  VF (attn PV):        flat = ((((head*64 + t64)*4 + nt)*2 + ks2)*64 + l)*8 + e
//      holds  V^T[head*64 + nt*16 + (l&15)][t64*64 + ks2*32 + (l>>4)*8 + e]
// Every attn/proj global load is then one contiguous 1 KB per instruction
// (was: 16 disjoint 64 B segments at 512 B row stride).
// ---------------------------------------------------------------------------

// ---------------------------------------------------------------------------
// prep: fp32 -> (bf16 hi, lo) split of a_z, bv_z, Wq/Wk/Wv, frag-major out.
// Thread handles one (tile, ki, l) item: reads 8 consecutive f32, writes one
// contiguous bf16x8 hi + lo (wave writes 4 KB contiguous).
// ---------------------------------------------------------------------------
__global__ __launch_bounds__(256) void prep_kernel(
    const float* __restrict__ a_z, const float* __restrict__ bv,
    const float* __restrict__ Wq, const float* __restrict__ Wk,
    const float* __restrict__ Wv,
    unsigned short* __restrict__ ah, unsigned short* __restrict__ al,
    unsigned short* __restrict__ bh, unsigned short* __restrict__ bl,
    unsigned short* __restrict__ wh, unsigned short* __restrict__ wl)
{
    const int idx = blockIdx.x * 256 + threadIdx.x;
    const int y = blockIdx.y;
    const float* __restrict__ src;
    unsigned short* __restrict__ dh;
    unsigned short* __restrict__ dl;
    int row, col;
    if (y == 0) {
        src = a_z; dh = ah; dl = al;
        row = (idx >> 9) * 16 + (idx & 15);
        col = ((idx >> 6) & 7) * 32 + ((idx >> 4) & 3) * 8;
    } else if (y == 1) {
        src = bv; dh = bh; dl = bl;
        row = (idx >> 9) * 16 + (idx & 15);
        col = ((idx >> 6) & 7) * 32 + ((idx >> 4) & 3) * 8;
    } else {
        if (idx >= 3 * 8192) return;
        const int m = idx >> 13;
        const int im = idx & 8191;
        src = (m == 0) ? Wq : ((m == 1) ? Wk : Wv);
        dh = wh; dl = wl;
        row = (im >> 9) * 16 + (im & 15);
        col = ((im >> 6) & 7) * 32 + ((im >> 4) & 3) * 8;
        // dest flat = m*65536 + im*8 == idx*8
    }
    f32x4 v0 = *(const f32x4*)(src + row * DIM + col);
    f32x4 v1 = *(const f32x4*)(src + row * DIM + col + 4);
    bf16x8 h8, l8;
    #pragma unroll
    for (int r = 0; r < 4; ++r) {
        unsigned short h0 = f2bf(v0[r]);
        h8[r] = (short)h0;  l8[r] = (short)f2bf(v0[r] - bf2f(h0));
        unsigned short h1 = f2bf(v1[r]);
        h8[4 + r] = (short)h1;  l8[4 + r] = (short)f2bf(v1[r] - bf2f(h1));
    }
    *(bf16x8*)(dh + idx * 8) = h8;
    *(bf16x8*)(dl + idx * 8) = l8;
}

// ---------------------------------------------------------------------------
// proj: pure bf16 MFMA GEMM, frag-major in AND out.
//   X*W^T ~= xh*wh + xl*wh + xh*wl   (term order identical to prior rounds)
// All loads: single base pointer + compile-time immediate offsets, each
// 1 KB lane-contiguous. A/B register double-buffer over ki retained.
// ---------------------------------------------------------------------------
__global__ __launch_bounds__(256, 2) void proj_kernel(
    const unsigned short* __restrict__ ah, const unsigned short* __restrict__ al,
    const unsigned short* __restrict__ bh, const unsigned short* __restrict__ bl,
    const unsigned short* __restrict__ whc, const unsigned short* __restrict__ wlc,
    unsigned short* __restrict__ qhi, unsigned short* __restrict__ qlo,
    unsigned short* __restrict__ khi, unsigned short* __restrict__ vtout)
{
    const int mat = blockIdx.z;
    const unsigned short* __restrict__ Xh = (mat == 0) ? ah : bh;
    const unsigned short* __restrict__ Xl = (mat == 0) ? al : bl;
    const unsigned short* __restrict__ Wh = whc + mat * 65536;
    const unsigned short* __restrict__ Wl = wlc + mat * 65536;

    const int tid  = threadIdx.x;
    const int wv   = tid >> 6;
    const int lane = tid & 63;
    const int c    = lane & 15;
    const int quad = lane >> 4;
    const int n0 = blockIdx.x * 64;
    const int by = blockIdx.y;

    // frag-major bases: X tile (n0>>4)+nt, W tile by*4+wv
    const unsigned short* xhp = Xh + (n0 >> 4) * 4096 + lane * 8;
    const unsigned short* xlp = Xl + (n0 >> 4) * 4096 + lane * 8;
    const unsigned short* whp = Wh + (by * 4 + wv) * 4096 + lane * 8;
    const unsigned short* wlp = Wl + (by * 4 + wv) * 4096 + lane * 8;

    f32x4 acc[4];
    #pragma unroll
    for (int nt = 0; nt < 4; ++nt) acc[nt] = (f32x4){0.f, 0.f, 0.f, 0.f};

    bf16x8 wAh, wAl, xAh[4], xAl[4];
    bf16x8 wBh, wBl, xBh[4], xBl[4];

    // preload ki = 0
    wAh = *(const bf16x8*)(whp);
    wAl = *(const bf16x8*)(wlp);
    #pragma unroll
    for (int nt = 0; nt < 4; ++nt) {
        xAh[nt] = *(const bf16x8*)(xhp + nt * 4096);
        xAl[nt] = *(const bf16x8*)(xlp + nt * 4096);
    }

    #pragma unroll
    for (int kk = 0; kk < 8; kk += 2) {
        wBh = *(const bf16x8*)(whp + (kk + 1) * 512);
        wBl = *(const bf16x8*)(wlp + (kk + 1) * 512);
        #pragma unroll
        for (int nt = 0; nt < 4; ++nt) {
            xBh[nt] = *(const bf16x8*)(xhp + nt * 4096 + (kk + 1) * 512);
            xBl[nt] = *(const bf16x8*)(xlp + nt * 4096 + (kk + 1) * 512);
        }
        #pragma unroll
        for (int nt = 0; nt < 4; ++nt) {
            acc[nt] = __builtin_amdgcn_mfma_f32_16x16x32_bf16(xAh[nt], wAh, acc[nt], 0, 0, 0);
            acc[nt] = __builtin_amdgcn_mfma_f32_16x16x32_bf16(xAl[nt], wAh, acc[nt], 0, 0, 0);
            acc[nt] = __builtin_amdgcn_mfma_f32_16x16x32_bf16(xAh[nt], wAl, acc[nt], 0, 0, 0);
        }
        if (kk + 2 < 8) {
            wAh = *(const bf16x8*)(whp + (kk + 2) * 512);
            wAl = *(const bf16x8*)(wlp + (kk + 2) * 512);
            #pragma unroll
            for (int nt = 0; nt < 4; ++nt) {
                xAh[nt] = *(const bf16x8*)(xhp + nt * 4096 + (kk + 2) * 512);
                xAl[nt] = *(const bf16x8*)(xlp + nt * 4096 + (kk + 2) * 512);
            }
        }
        #pragma unroll
        for (int nt = 0; nt < 4; ++nt) {
            acc[nt] = __builtin_amdgcn_mfma_f32_16x16x32_bf16(xBh[nt], wBh, acc[nt], 0, 0, 0);
            acc[nt] = __builtin_amdgcn_mfma_f32_16x16x32_bf16(xBl[nt], wBh, acc[nt], 0, 0, 0);
            acc[nt] = __builtin_amdgcn_mfma_f32_16x16x32_bf16(xBh[nt], wBl, acc[nt], 0, 0, 0);
        }
    }

    // epilogue: value(n = n0+nt*16+quad*4+r, j = by*64+wv*16+c)
    if (mat != 2) {
        // QF/KF: head=by, ks=wv>>1, l = ((wv&1)*2+(c>>3))*16 + quad*4+r, e=c&7
        const int ks = wv >> 1;
        const int lq = ((wv & 1) * 2 + (c >> 3)) * 16 + quad * 4;
        const int e  = c & 7;
        #pragma unroll
        for (int nt = 0; nt < 4; ++nt) {
            const int tbase = (((by * 256 + (n0 >> 4) + nt) * 2 + ks) * 64 + lq) * 8 + e;
            #pragma unroll
            for (int r = 0; r < 4; ++r) {
                const int idx = tbase + r * 8;
                if (mat == 0) {
                    unsigned short h = f2bf(acc[nt][r]);
                    qhi[idx] = h;
                    qlo[idx] = f2bf(acc[nt][r] - bf2f(h));
                } else {
                    khi[idx] = f2bf(acc[nt][r]);
                }
            }
        }
    } else {
        // VF: head=by, t64=n0>>6, v_nt=wv, ks2=nt>>1,
        //     l = ((nt&1)*2+(quad>>1))*16 + c, e = (quad&1)*4 + r
        #pragma unroll
        for (int nt = 0; nt < 4; ++nt) {
            const int lv = ((nt & 1) * 2 + (quad >> 1)) * 16 + c;
            const int idx = ((((by * 64 + (n0 >> 6)) * 4 + wv) * 2 + (nt >> 1)) * 64 + lv) * 8
                            + (quad & 1) * 4;
            us4 p;
            #pragma unroll
            for (int r = 0; r < 4; ++r) p[r] = f2bf(acc[nt][r]);
            *(us4*)(vtout + idx) = p;
        }
    }
}

// ---------------------------------------------------------------------------
// attn v4: frag-major K/V/Q -> every global load is 1 KB lane-contiguous;
// a wave-iter's K (and V) is one contiguous 4 KB block. NSPLIT=8 (2048
// blocks, 8/CU nominal) for latency hiding + half-size tail. Issue groups
// K -> V -> next-wm with sched_barrier fences (round-4 structure kept).
// den via ones-column MFMA. wm folded+staged in LDS, shared by 4 heads.
// ---------------------------------------------------------------------------
__global__ __launch_bounds__(256, 2) void attn_kernel(
    const unsigned short* __restrict__ qhg,
    const unsigned short* __restrict__ qlg,
    const unsigned short* __restrict__ kg,
    const unsigned short* __restrict__ vtg,
    const float* __restrict__ wg,
    const int* __restrict__ mg,
    float* __restrict__ pnum,
    float* __restrict__ pden)
{
    __shared__ float wmbuf[2][16 * WSTR];
    __shared__ unsigned short pbuf[4][16 * PSTR];

    const int tid  = threadIdx.x;
    const int wv   = tid >> 6;      // head
    const int lane = tid & 63;
    const int c    = lane & 15;
    const int quad = lane >> 4;

    // bijective XCD swizzle: XCD x gets b-split x, all 256 a-tiles
    const int flat = blockIdx.y * 256 + blockIdx.x;
    const int swz  = (flat & 7) * 256 + (flat >> 3);
    const int a0   = (swz & 255) * 16;
    const int bs   = swz >> 8;
    const int bbase = bs * (NB / NSPLIT);

    // staging mapping: thread t handles (row sa, cols sb..sb+3) of 16x64 tile
    const int sa = tid >> 4;
    const int sb = (tid & 15) * 4;

    // frag-major bases (element indices)
    unsigned kbase = (unsigned)((wv * 256 + (bbase >> 4)) * 1024 + lane * 8);
    unsigned vbase = (unsigned)((wv * 64 + (bbase >> 6)) * 4096 + lane * 8);
    const unsigned qbase = (unsigned)((wv * 256 + (a0 >> 4)) * 1024 + lane * 8);

    bf16x8 qh[2], ql[2];
    qh[0] = *(const bf16x8*)(qhg + qbase);
    qh[1] = *(const bf16x8*)(qhg + qbase + 512);
    ql[0] = *(const bf16x8*)(qlg + qbase);
    ql[1] = *(const bf16x8*)(qlg + qbase + 512);

    // bf16 1.0 splat for the den (ones-column) MFMA
    bf16x8 ones;
    #pragma unroll
    for (int r = 0; r < 8; ++r) ones[r] = (short)0x3F80;

    f32x4 num[4];
    #pragma unroll
    for (int nt = 0; nt < 4; ++nt) num[nt] = (f32x4){0.f, 0.f, 0.f, 0.f};
    f32x4 dacc = (f32x4){0.f, 0.f, 0.f, 0.f};

    unsigned woff = (unsigned)((a0 + sa) * NB + bbase + sb);

    // prologue: stage wm tile 0
    {
        f32x4 w = *(const f32x4*)(wg + woff);
        i32x4 m = *(const i32x4*)(mg + woff);
        f32x4 wm;
        #pragma unroll
        for (int r = 0; r < 4; ++r) wm[r] = m[r] ? w[r] : -1.0e9f;
        *(f32x4*)(&wmbuf[0][sa * WSTR + sb]) = wm;
    }
    woff += 64;

    for (int it = 0; it < BIT; ++it) {
        const int cur = it & 1;
        const bool more = (it + 1 < BIT);
        __syncthreads();   // wmbuf[cur] ready; wmbuf[cur^1] free

        // --- group 1: K loads (one contiguous 4 KB block per wave) ---
        bf16x8 kf[4][2];
        #pragma unroll
        for (int bt = 0; bt < 4; ++bt)
            #pragma unroll
            for (int ks = 0; ks < 2; ++ks)
                kf[bt][ks] = *(const bf16x8*)(kg + kbase + bt * 1024 + ks * 512);
        __builtin_amdgcn_sched_barrier(0);

        // --- group 2: V loads (one contiguous 4 KB block per wave) ---
        bf16x8 vf[4][2];
        #pragma unroll
        for (int nt = 0; nt < 4; ++nt)
            #pragma unroll
            for (int ks2 = 0; ks2 < 2; ++ks2)
                vf[nt][ks2] = *(const bf16x8*)(vtg + vbase + nt * 1024 + ks2 * 512);
        __builtin_amdgcn_sched_barrier(0);

        // --- group 3: next-tile w/m (consumed last, at the ds_write) ---
        f32x4 wnxt; i32x4 mnxt;
        if (more) {
            wnxt = *(const f32x4*)(wg + woff);
            mnxt = *(const i32x4*)(mg + woff);
        }
        __builtin_amdgcn_sched_barrier(0);

        kbase += 4096;
        vbase += 4096;
        woff  += 64;

        // wm fragments from LDS
        f32x4 wf[4];
        #pragma unroll
        for (int bt = 0; bt < 4; ++bt)
            wf[bt] = *(const f32x4*)(&wmbuf[cur][c * WSTR + bt * 16 + quad * 4]);

        // S^T = K*(Qhi)^T + K*(Qlo)^T
        f32x4 S[4];
        __builtin_amdgcn_s_setprio(1);
        #pragma unroll
        for (int bt = 0; bt < 4; ++bt) {
            f32x4 s = (f32x4){0.f, 0.f, 0.f, 0.f};
            s = __builtin_amdgcn_mfma_f32_16x16x32_bf16(kf[bt][0], qh[0], s, 0, 0, 0);
            s = __builtin_amdgcn_mfma_f32_16x16x32_bf16(kf[bt][1], qh[1], s, 0, 0, 0);
            s = __builtin_amdgcn_mfma_f32_16x16x32_bf16(kf[bt][0], ql[0], s, 0, 0, 0);
            s = __builtin_amdgcn_mfma_f32_16x16x32_bf16(kf[bt][1], ql[1], s, 0, 0, 0);
            S[bt] = s;
        }
        __builtin_amdgcn_s_setprio(0);

        // elementwise: lane holds (a = c, b = bt*16 + quad*4 + r)
        #pragma unroll
        for (int bt = 0; bt < 4; ++bt) {
            us4 p;
            #pragma unroll
            for (int r = 0; r < 4; ++r) {
                float t = fmaf(S[bt][r], 0.125f, wf[bt][r]);
                t = __builtin_amdgcn_fmed3f(t, -10.0f, 10.0f);
                float e = exp2f(t * 1.4426950408889634f);
                p[r] = f2bf(e);
            }
            *(us4*)(&pbuf[wv][c * PSTR + bt * 16 + quad * 4]) = p;
        }

        // PV + den: A-frags from wave-private P (no barrier)
        bf16x8 pf[2];
        #pragma unroll
        for (int ks2 = 0; ks2 < 2; ++ks2)
            pf[ks2] = *(const bf16x8*)(&pbuf[wv][c * PSTR + ks2 * 32 + quad * 8]);
        __builtin_amdgcn_s_setprio(1);
        #pragma unroll
        for (int nt = 0; nt < 4; ++nt) {
            num[nt] = __builtin_amdgcn_mfma_f32_16x16x32_bf16(pf[0], vf[nt][0], num[nt], 0, 0, 0);
            num[nt] = __builtin_amdgcn_mfma_f32_16x16x32_bf16(pf[1], vf[nt][1], num[nt], 0, 0, 0);
        }
        dacc = __builtin_amdgcn_mfma_f32_16x16x32_bf16(pf[0], ones, dacc, 0, 0, 0);
        dacc = __builtin_amdgcn_mfma_f32_16x16x32_bf16(pf[1], ones, dacc, 0, 0, 0);
        __builtin_amdgcn_s_setprio(0);

        // write next wm tile (all waves passed top barrier; waits only on wm)
        if (more) {
            f32x4 wm;
            #pragma unroll
            for (int r = 0; r < 4; ++r) wm[r] = mnxt[r] ? wnxt[r] : -1.0e9f;
            *(f32x4*)(&wmbuf[cur ^ 1][sa * WSTR + sb]) = wm;
        }
    }

    // den: dacc C-layout row = quad*4+r = a-offset, every col holds a copy
    const int hb = (bs * 4 + wv) * NA + a0;
    if (c == 0) {
        #pragma unroll
        for (int r = 0; r < 4; ++r)
            pden[hb + quad * 4 + r] = dacc[r];
    }

    // num C-layout: col = lane&15 = dk-sub, row = quad*4+r = a
    #pragma unroll
    for (int nt = 0; nt < 4; ++nt)
        #pragma unroll
        for (int r = 0; r < 4; ++r)
            pnum[(size_t)(hb + quad * 4 + r) * DK + nt * 16 + c] = num[nt][r];
}

// ---------------------------------------------------------------------------
// reduce: combine b-split partials, divide, average heads; influence = 1.0
// ---------------------------------------------------------------------------
__global__ __launch_bounds__(256) void reduce_kernel(
    const float* __restrict__ pnum, const float* __restrict__ pden,
    float* __restrict__ outp)
{
    const int idx = blockIdx.x * 256 + threadIdx.x;   // over NA*DK
    const int a = idx >> 6, dd = idx & 63;
    float s = 0.0f;
    #pragma unroll
    for (int h = 0; h < 4; ++h) {
        float n = 0.0f, d = 0.0f;
        #pragma unroll
        for (int b = 0; b < NSPLIT; ++b) {
            n += pnum[(size_t)((b * 4 + h) * NA + a) * DK + dd];
            d += pden[(b * 4 + h) * NA + a];
        }
        s += n / d;
    }
    outp[idx] = 0.25f * s;
    if (dd == 0) outp[NA * DK + a] = 1.0f;   // softmax rows sum to 1
}

extern "C" void kernel_launch(void* const* d_in, const int* in_sizes, int n_in,
                              void* d_out, int out_size, void* d_ws, size_t ws_size,
                              hipStream_t stream) {
    const float* a_z = (const float*)d_in[0];
    const float* bv  = (const float*)d_in[1];
    const int* mask  = (const int*)d_in[2];
    const float* wgt = (const float*)d_in[3];
    const float* Wq  = (const float*)d_in[4];
    const float* Wk  = (const float*)d_in[5];
    const float* Wv  = (const float*)d_in[6];
    float* out = (float*)d_out;

    // persistent attn inputs
    unsigned short* qhi = (unsigned short*)d_ws;       // QF hi [4][256][2][64][8]
    unsigned short* qlo = qhi + NA * DIM;              // QF lo
    unsigned short* khi = qlo + NA * DIM;              // KF
    unsigned short* vt  = khi + NB * DIM;              // VF
    float* pnum = (float*)(vt + (size_t)DIM * NB);     // [NSPLIT][4][NA][DK]
    float* pden = pnum + (size_t)NSPLIT * 4 * NA * DK; // [NSPLIT][4][NA]
    // prep/proj scratch overlapped INSIDE pnum (proj finishes before attn
    // writes pnum; stream-ordered => safe). Span 9.2 MB < pnum 33.5 MB.
    unsigned short* ah  = (unsigned short*)pnum;       // XF a hi
    unsigned short* al  = ah + NA * DIM;
    unsigned short* bh  = al + NA * DIM;
    unsigned short* bl  = bh + NB * DIM;
    unsigned short* whc = bl + NB * DIM;               // WF [3][16][8][64][8]
    unsigned short* wlc = whc + 3 * 65536;

    prep_kernel<<<dim3(512, 3), 256, 0, stream>>>(a_z, bv, Wq, Wk, Wv,
                                                  ah, al, bh, bl, whc, wlc);
    proj_kernel<<<dim3(64, 4, 3), 256, 0, stream>>>(ah, al, bh, bl, whc, wlc,
                                                    qhi, qlo, khi, vt);
    attn_kernel<<<dim3(256, NSPLIT), 256, 0, stream>>>(qhi, qlo, khi, vt,
                                                       wgt, mask, pnum, pden);
    reduce_kernel<<<dim3(NA * DK / 256), 256, 0, stream>>>(pnum, pden, out);
}